// Round 7
// baseline (221.462 us; speedup 1.0000x reference)
//
#include <hip/hip_runtime.h>

// Problem constants (fixed by the reference setup)
#define B_   16
#define C_   64
#define H_   128
#define W_   128
#define HO   126
#define WO   126
#define NK   8     // number of conv kernels
#define HALF 63    // output rows per wave-task (126 = 2*63)

// No-LDS streaming conv. One wave per (c, b, k, half-plane): lane l computes
// wo = l and wo = 64+l via a 3-row rolling register window read directly from
// global (L1/L2-resident; each input row loaded once per wave), SiLU applied
// at load time. One-iteration load prefetch (p->q) hides L1/L2 latency.
// No barriers, no LDS: each wave writes one contiguous ~32 KB output stream.
__device__ __forceinline__ float silu_f(float t) {
    return t * __builtin_amdgcn_rcpf(1.0f + __expf(-t));
}

__global__ __launch_bounds__(256) void conv_silu_kernel(
    const float* __restrict__ x, const float* __restrict__ Wt,
    float* __restrict__ out)
{
    const int tid  = threadIdx.x;
    const int l    = tid & 63;
    const int wv   = tid >> 6;                 // 0..3
    const int half = blockIdx.x & 1;           // 0..1 : row-half of the plane
    const int kgrp = blockIdx.x >> 1;          // 0..1 : kernel group
    const int c    = blockIdx.y;
    const int b    = blockIdx.z;
    const int k    = __builtin_amdgcn_readfirstlane(kgrp * 4 + wv);

    // weights: uniform address -> scalar loads into SGPRs
    float w9[9];
#pragma unroll
    for (int j = 0; j < 9; ++j) w9[j] = Wt[k * 9 + j];

    const float* xp = x + (size_t)(b * C_ + c) * H_ * W_;
    float*       op = out + (size_t)((b * C_ + c) * NK + k) * HO * WO;

    const int r0 = half * HALF;                // first output row of this task

    // tap columns; B-half wraps (&127) to stay in-bounds — lanes whose B
    // output is discarded (l >= 62) read wrapped junk, never stored.
    const int ca  = l;
    const int cb0 = (64 + l)     & 127;
    const int cb1 = (64 + l + 1) & 127;
    const int cb2 = (64 + l + 2) & 127;

    // rolling 3-row SiLU'd tap window
    float tA[3][3], tB[3][3];
#pragma unroll
    for (int j = 0; j < 2; ++j) {
        const float* rp = xp + (size_t)(r0 + j) * W_;
        tA[j][0] = silu_f(rp[ca]);  tA[j][1] = silu_f(rp[ca + 1]);  tA[j][2] = silu_f(rp[ca + 2]);
        tB[j][0] = silu_f(rp[cb0]); tB[j][1] = silu_f(rp[cb1]);     tB[j][2] = silu_f(rp[cb2]);
    }
    // pending raw loads of input row r0+2
    float pA0, pA1, pA2, pB0, pB1, pB2;
    {
        const float* rp = xp + (size_t)(r0 + 2) * W_;
        pA0 = rp[ca];  pA1 = rp[ca + 1]; pA2 = rp[ca + 2];
        pB0 = rp[cb0]; pB1 = rp[cb1];    pB2 = rp[cb2];
    }

#pragma unroll 3
    for (int r = 0; r < HALF; ++r) {
        // issue next row's loads early (input row r0+r+3, clamped in-bounds;
        // the clamp only triggers on the final iteration, values unused)
        const int rn = (r0 + r + 3 < H_) ? (r0 + r + 3) : (H_ - 1);
        const float* rp = xp + (size_t)rn * W_;
        const float qA0 = rp[ca],  qA1 = rp[ca + 1], qA2 = rp[ca + 2];
        const float qB0 = rp[cb0], qB1 = rp[cb1],    qB2 = rp[cb2];

        // finish the window with the pending row (SiLU now)
        tA[2][0] = silu_f(pA0); tA[2][1] = silu_f(pA1); tA[2][2] = silu_f(pA2);
        tB[2][0] = silu_f(pB0); tB[2][1] = silu_f(pB1); tB[2][2] = silu_f(pB2);

        float accA = 0.f, accB = 0.f;
#pragma unroll
        for (int j = 0; j < 3; ++j) {
#pragma unroll
            for (int d = 0; d < 3; ++d) {
                const float ww = w9[j * 3 + d];
                accA += ww * tA[j][d];
                accB += ww * tB[j][d];
            }
        }

        float* orow = op + (size_t)(r0 + r) * WO;
        orow[l] = accA;                        // wo = 0..63
        if (l < 62) orow[64 + l] = accB;       // wo = 64..125

        // rotate window; promote pending loads
#pragma unroll
        for (int d = 0; d < 3; ++d) {
            tA[0][d] = tA[1][d]; tA[1][d] = tA[2][d];
            tB[0][d] = tB[1][d]; tB[1][d] = tB[2][d];
        }
        pA0 = qA0; pA1 = qA1; pA2 = qA2;
        pB0 = qB0; pB1 = qB1; pB2 = qB2;
    }
}

extern "C" void kernel_launch(void* const* d_in, const int* in_sizes, int n_in,
                              void* d_out, int out_size, void* d_ws, size_t ws_size,
                              hipStream_t stream) {
    const float* x  = (const float*)d_in[0];   // [16,64,128,128] f32
    const float* Wt = (const float*)d_in[1];   // [8,9] f32
    float* out = (float*)d_out;                // [16,512,126,126] f32

    dim3 grid(4, C_, B_);   // (half x kgroup, channel, batch)
    conv_silu_kernel<<<grid, 256, 0, stream>>>(x, Wt, out);
}

// Round 8
// 145.220 us; speedup vs baseline: 1.5250x; 1.5250x over previous
//
#include <hip/hip_runtime.h>

// Problem constants (fixed by the reference setup)
#define B_   16
#define C_   64
#define H_   128
#define W_   128
#define HO   126
#define WO   126
#define NK   8     // number of conv kernels
#define ROWS 14    // output rows per band (126 = 9 * 14)
#define INR  16    // input rows staged = ROWS + 2

// Block = (band, channel, batch), 512 threads = 8 waves, ZERO barriers.
// Each wave stages its OWN private copy of the 16x128 input band into LDS
// (8 float4 loads/lane, SiLU applied, ds_write_b128), so a wave waits only on
// its own vmcnt — no block-wide stage/barrier window that starves the store
// pipe. Compute/write structure identical to the round-3 winner: wave w owns
// kernel-plane k=w, lane l computes wo=l and wo=64+l via a rolling 3-row tap
// window (6 LDS reads/row), weights in SGPRs, one contiguous 7 KB write
// stream per wave. LDS 64 KiB/block -> 2 blocks/CU (write BW saturates at
// ~11% occupancy per the fill kernels, so 16 waves/CU is ample).
__device__ __forceinline__ float silu_f(float t) {
    return t * __builtin_amdgcn_rcpf(1.0f + __expf(-t));
}

__global__ __launch_bounds__(512) void conv_silu_kernel(
    const float* __restrict__ x, const float* __restrict__ Wt,
    float* __restrict__ out)
{
    __shared__ float s[NK][INR][W_];   // 8 waves x 8 KiB private = 64 KiB

    const int band = blockIdx.x;   // 0..8
    const int c    = blockIdx.y;   // 0..63
    const int b    = blockIdx.z;   // 0..15
    const int tid  = threadIdx.x;  // 0..511
    const int l    = tid & 63;
    const int ws   = __builtin_amdgcn_readfirstlane((int)(threadIdx.x >> 6));
    const int ho0  = band * ROWS;

    // weights: uniform address -> scalar loads into SGPRs
    float w9[9];
#pragma unroll
    for (int j = 0; j < 9; ++j) w9[j] = Wt[ws * 9 + j];

    // ---- wave-private staging: 16 rows x 128 cols, 512 float4, 8 per lane ----
    // Always in-bounds: ho0 max = 112, +15 = 127 = H-1.
    {
        const float4* xv =
            (const float4*)(x + ((size_t)(b * C_ + c) * H_ + ho0) * W_);
        float4 v[8];
#pragma unroll
        for (int j = 0; j < 8; ++j) v[j] = xv[l + j * 64];
#pragma unroll
        for (int j = 0; j < 8; ++j) {
            const int f   = l + j * 64;          // float4 index 0..511
            const int row = f >> 5;              // 32 float4 per row
            const int col = (f & 31) << 2;
            float4 sv;
            sv.x = silu_f(v[j].x);
            sv.y = silu_f(v[j].y);
            sv.z = silu_f(v[j].z);
            sv.w = silu_f(v[j].w);
            *(float4*)&s[ws][row][col] = sv;     // ds_write_b128
        }
    }
    // no __syncthreads(): each wave reads only what it wrote; the compiler
    // inserts the lgkmcnt waits for the ds_write -> ds_read dependency.

    float* op = out + ((size_t)((b * C_ + c) * NK + ws) * HO + ho0) * WO;

    // Rolling tap window: t*[j][d] = silu(x)[input row r+j][wo + d]
    float tA[3][3], tB[3][3];
#pragma unroll
    for (int j = 0; j < 3; ++j) {
#pragma unroll
        for (int d = 0; d < 3; ++d) {
            tA[j][d] = s[ws][j][l + d];                // cols 0..65, in-bounds
            tB[j][d] = s[ws][j][(64 + l + d) & 127];   // masked lanes junk, ok
        }
    }

#pragma unroll
    for (int r = 0; r < ROWS; ++r) {
        float accA = 0.f, accB = 0.f;
#pragma unroll
        for (int j = 0; j < 3; ++j) {
#pragma unroll
            for (int d = 0; d < 3; ++d) {
                const float ww = w9[j * 3 + d];
                accA += ww * tA[j][d];
                accB += ww * tB[j][d];
            }
        }
        op[r * WO + l] = accA;                     // wo = 0..63
        if (l < 62) op[r * WO + 64 + l] = accB;    // wo = 64..125

        if (r < ROWS - 1) {
            // rotate window and pull in input row r+3 (max 15 = INR-1)
#pragma unroll
            for (int j = 0; j < 2; ++j) {
#pragma unroll
                for (int d = 0; d < 3; ++d) {
                    tA[j][d] = tA[j + 1][d];
                    tB[j][d] = tB[j + 1][d];
                }
            }
#pragma unroll
            for (int d = 0; d < 3; ++d) {
                tA[2][d] = s[ws][r + 3][l + d];
                tB[2][d] = s[ws][r + 3][(64 + l + d) & 127];
            }
        }
    }
}

extern "C" void kernel_launch(void* const* d_in, const int* in_sizes, int n_in,
                              void* d_out, int out_size, void* d_ws, size_t ws_size,
                              hipStream_t stream) {
    const float* x  = (const float*)d_in[0];   // [16,64,128,128] f32
    const float* Wt = (const float*)d_in[1];   // [8,9] f32
    float* out = (float*)d_out;                // [16,512,126,126] f32

    dim3 grid(9, C_, B_);   // (bands, channels, batch)
    conv_silu_kernel<<<grid, 512, 0, stream>>>(x, Wt, out);
}

// Round 9
// 116.520 us; speedup vs baseline: 1.9006x; 1.2463x over previous
//
#include <hip/hip_runtime.h>

// Problem constants (fixed by the reference setup)
#define B_   16
#define C_   64
#define H_   128
#define W_   128
#define HO   126
#define WO   126
#define NK   8     // number of conv kernels
#define ROWS 14    // output rows per block (126 = 9 * 14)
#define INR  16    // input rows staged = ROWS + 2

// Round-3 winner (116.6 us), reverted verbatim after R4-R8 structural probes
// all regressed (coarser bands 124.9, persistent dbuf 139.5, finer blocks
// 129.9, no-LDS 221.5, wave-private LDS 145.2).
//
// Block = (band, channel, batch), 512 threads = 8 waves.
// Wave w owns output kernel-plane k=w for the whole band: it writes a single
// contiguous, monotonically ascending 7 KB stream (14 rows x 504 B).
// Lane l computes wo = l and wo = 64+l via a rolling 3-row tap window held in
// registers (6 LDS reads per row). Weights live in SGPRs (readfirstlane'd
// wave index -> scalar loads), so v_fma uses SGPR*VGPR.
__global__ __launch_bounds__(512) void conv_silu_kernel(
    const float* __restrict__ x, const float* __restrict__ Wt,
    float* __restrict__ out)
{
    __shared__ float s[INR][W_];   // 16 * 128 * 4 B = 8 KiB

    const int band = blockIdx.x;   // 0..8
    const int c    = blockIdx.y;   // 0..63
    const int b    = blockIdx.z;   // 0..15
    const int tid  = threadIdx.x;  // 0..511
    const int ho0  = band * ROWS;

    // ---- stage input band (16 rows x 128 cols) with SiLU applied ----
    // 2048 floats = 512 float4; one per thread. Always in-bounds
    // (ho0 max = 112, +15 = 127 = H-1).
    {
        const float4* xv =
            (const float4*)(x + ((size_t)(b * C_ + c) * H_ + ho0) * W_);
        const float4 v = xv[tid];
        const int row = tid >> 5;            // 32 float4 per row
        const int col = (tid & 31) << 2;
        float4 sv;
        sv.x = v.x * __builtin_amdgcn_rcpf(1.0f + __expf(-v.x));
        sv.y = v.y * __builtin_amdgcn_rcpf(1.0f + __expf(-v.y));
        sv.z = v.z * __builtin_amdgcn_rcpf(1.0f + __expf(-v.z));
        sv.w = v.w * __builtin_amdgcn_rcpf(1.0f + __expf(-v.w));
        *(float4*)&s[row][col] = sv;         // ds_write_b128
    }
    __syncthreads();

    // ---- compute: wave w handles kernel k = w ----
    const int l  = tid & 63;
    const int ws = __builtin_amdgcn_readfirstlane((int)(threadIdx.x >> 6)); // SGPR

    float w9[9];  // scalar loads (uniform address) -> SGPRs
#pragma unroll
    for (int j = 0; j < 9; ++j) w9[j] = Wt[ws * 9 + j];

    float* op = out + ((size_t)((b * C_ + c) * NK + ws) * HO + ho0) * WO;

    // Rolling tap window: t*[j][d] = silu(x)[input row r+j][wo + d]
    float tA[3][3], tB[3][3];
#pragma unroll
    for (int j = 0; j < 3; ++j) {
#pragma unroll
        for (int d = 0; d < 3; ++d) {
            tA[j][d] = s[j][l + d];                // cols 0..65, in-bounds
            tB[j][d] = s[j][(64 + l + d) & 127];   // masked lanes read junk, ok
        }
    }

#pragma unroll
    for (int r = 0; r < ROWS; ++r) {
        float accA = 0.f, accB = 0.f;
#pragma unroll
        for (int j = 0; j < 3; ++j) {
#pragma unroll
            for (int d = 0; d < 3; ++d) {
                const float ww = w9[j * 3 + d];
                accA += ww * tA[j][d];
                accB += ww * tB[j][d];
            }
        }
        op[r * WO + l] = accA;                     // wo = 0..63
        if (l < 62) op[r * WO + 64 + l] = accB;    // wo = 64..125

        if (r < ROWS - 1) {
            // rotate window and pull in input row r+3 (max 15 = INR-1)
#pragma unroll
            for (int j = 0; j < 2; ++j) {
#pragma unroll
                for (int d = 0; d < 3; ++d) {
                    tA[j][d] = tA[j + 1][d];
                    tB[j][d] = tB[j + 1][d];
                }
            }
#pragma unroll
            for (int d = 0; d < 3; ++d) {
                tA[2][d] = s[r + 3][l + d];
                tB[2][d] = s[r + 3][(64 + l + d) & 127];
            }
        }
    }
}

extern "C" void kernel_launch(void* const* d_in, const int* in_sizes, int n_in,
                              void* d_out, int out_size, void* d_ws, size_t ws_size,
                              hipStream_t stream) {
    const float* x  = (const float*)d_in[0];   // [16,64,128,128] f32
    const float* Wt = (const float*)d_in[1];   // [8,9] f32
    float* out = (float*)d_out;                // [16,512,126,126] f32

    dim3 grid(9, C_, B_);   // (bands, channels, batch)
    conv_silu_kernel<<<grid, 512, 0, stream>>>(x, Wt, out);
}